// Round 1
// baseline (77.123 us; speedup 1.0000x reference)
//
#include <hip/hip_runtime.h>

// CCM: causal 3x3 complex multi-frame filter.
// out[b,f,t,:] = sum_{i,j} (Hr+i*Hi)[b,i,j,t,f] * x[b, f+j-1, t+i-2, :]
// Hr = a0 - 0.5*(a1+a2); Hi = (sqrt(3)/2)*(a1-a2); a_k = m[b, 9k+3i+j, t, f]

constexpr int B = 8, C = 27, T = 1000, F = 257;
constexpr int TCH = 8;           // t-chunk per thread -> 64B coalesced line write
constexpr int NT = T / TCH;      // 125

__global__ __launch_bounds__(256)
void ccm_kernel(const float* __restrict__ m,
                const float* __restrict__ x,
                float* __restrict__ out) {
    const int tid = blockIdx.x * blockDim.x + threadIdx.x;
    const int total = B * NT * F;
    if (tid >= total) return;

    const int f   = tid % F;
    const int rem = tid / F;
    const int tc  = rem % NT;
    const int b   = rem / NT;
    const int t0  = tc * TCH;

    const float SQ3_2 = 0.8660254037844386f;

    const bool vf0 = (f >= 1);       // f-1 valid
    const bool vf2 = (f + 1 < F);    // f+1 valid

    const float* xb = x + (size_t)b * F * T * 2;

    // sliding window over time taps: row p=0 -> t-2, p=1 -> t-1, p=2 -> t
    float wr[3][3], wi[3][3];

    auto loadrow = [&](int tt, int p) {
        #pragma unroll
        for (int j = 0; j < 3; ++j) {
            const int ff = f + j - 1;
            const bool okf = (j == 0) ? vf0 : ((j == 2) ? vf2 : true);
            if (tt >= 0 && okf) {
                const float2 val = *reinterpret_cast<const float2*>(
                    xb + ((size_t)ff * T + tt) * 2);
                wr[p][j] = val.x;
                wi[p][j] = val.y;
            } else {
                wr[p][j] = 0.0f;
                wi[p][j] = 0.0f;
            }
        }
    };

    loadrow(t0 - 2, 0);
    loadrow(t0 - 1, 1);

    const float* mb = m + ((size_t)b * C * T + t0) * F + f;
    constexpr size_t CSTRIDE = (size_t)T * F;   // per-channel stride in m

    float2 res[TCH];

    #pragma unroll
    for (int u = 0; u < TCH; ++u) {
        const int t = t0 + u;
        loadrow(t, 2);                           // newest row (t >= 0 always)
        const float* mp = mb + (size_t)u * F;

        float accr = 0.0f, acci = 0.0f;
        #pragma unroll
        for (int i = 0; i < 3; ++i) {
            #pragma unroll
            for (int j = 0; j < 3; ++j) {
                const int n = i * 3 + j;
                const float a0 = mp[(size_t)(0 * 9 + n) * CSTRIDE];
                const float a1 = mp[(size_t)(1 * 9 + n) * CSTRIDE];
                const float a2 = mp[(size_t)(2 * 9 + n) * CSTRIDE];
                const float hr = a0 - 0.5f * (a1 + a2);
                const float hi = SQ3_2 * (a1 - a2);
                const float xr = wr[i][j], xi = wi[i][j];
                accr += hr * xr - hi * xi;
                acci += hr * xi + hi * xr;
            }
        }
        res[u] = make_float2(accr, acci);

        // shift window
        #pragma unroll
        for (int j = 0; j < 3; ++j) {
            wr[0][j] = wr[1][j]; wi[0][j] = wi[1][j];
            wr[1][j] = wr[2][j]; wi[1][j] = wi[2][j];
        }
    }

    // contiguous 64B write: out[b, f, t0..t0+7, 0..1]
    float* op = out + ((size_t)(b * F + f) * T + t0) * 2;
    #pragma unroll
    for (int u = 0; u < TCH / 2; ++u) {
        reinterpret_cast<float4*>(op)[u] =
            make_float4(res[2 * u].x, res[2 * u].y,
                        res[2 * u + 1].x, res[2 * u + 1].y);
    }
}

extern "C" void kernel_launch(void* const* d_in, const int* in_sizes, int n_in,
                              void* d_out, int out_size, void* d_ws, size_t ws_size,
                              hipStream_t stream) {
    const float* m = (const float*)d_in[0];
    const float* x = (const float*)d_in[1];
    // d_in[2] = v is a fixed compile-time constant per the reference.
    float* out = (float*)d_out;

    const int total = B * NT * F;          // 257,000 threads
    const int block = 256;
    const int grid = (total + block - 1) / block;
    ccm_kernel<<<grid, block, 0, stream>>>(m, x, out);
}